// Round 3
// baseline (468.245 us; speedup 1.0000x reference)
//
#include <hip/hip_runtime.h>
#include <math.h>

#define BATCH 256
#define NNODE 128
#define NT    32768      // BATCH*NNODE
#define FDIM  128
#define NEDGE 262144
#define LBL   29
#define MAXDEG 16
#define RWD   16
#define NTF   (NT * FDIM)

// ---------------------------------------------------------------- CSR build (side-fused)
__global__ void k_deg2(const int* __restrict__ dst1, const int* __restrict__ dst2,
                       int* __restrict__ d1, int* __restrict__ d2) {
  int e = blockIdx.x * 256 + threadIdx.x;
  if (e < NEDGE) atomicAdd(&d1[dst1[e]], 1);
  else if (e < 2 * NEDGE) atomicAdd(&d2[dst2[e - NEDGE]], 1);
}
// scan + dinv fused (scan already loads every degi value)
__global__ __launch_bounds__(1024) void k_scan2(const int* __restrict__ degi1,
                                                int* __restrict__ ofs1, int* __restrict__ cur1,
                                                float* __restrict__ dinv1,
                                                const int* __restrict__ degi2,
                                                int* __restrict__ ofs2, int* __restrict__ cur2,
                                                float* __restrict__ dinv2) {
  const int* degi = blockIdx.x ? degi2 : degi1;
  int* ofs   = blockIdx.x ? ofs2  : ofs1;
  int* cur   = blockIdx.x ? cur2  : cur1;
  float* dnv = blockIdx.x ? dinv2 : dinv1;
  __shared__ int part[1024];
  int t = threadIdx.x;
  int base = t * 32;
  int loc[32]; int sum = 0;
#pragma unroll
  for (int u = 0; u < 32; ++u) {
    int dg = degi[base + u];
    loc[u] = sum; sum += dg;
    dnv[base + u] = rsqrtf((float)(dg + 1));   // +1 self loop
  }
  part[t] = sum;
  __syncthreads();
  for (int off = 1; off < 1024; off <<= 1) {
    int v = (t >= off) ? part[t - off] : 0;
    __syncthreads();
    part[t] += v;
    __syncthreads();
  }
  int excl = (t == 0) ? 0 : part[t - 1];
#pragma unroll
  for (int u = 0; u < 32; ++u) {
    int o = excl + loc[u];
    ofs[base + u] = o; cur[base + u] = o;
  }
}
__global__ void k_fill2(const int* __restrict__ src1, const int* __restrict__ dst1,
                        int* __restrict__ cur1, int* __restrict__ csr1,
                        const int* __restrict__ src2, const int* __restrict__ dst2,
                        int* __restrict__ cur2, int* __restrict__ csr2) {
  int e = blockIdx.x * 256 + threadIdx.x;
  if (e < NEDGE) {
    int pos = atomicAdd(&cur1[dst1[e]], 1);
    csr1[pos] = src1[e];
  } else if (e < 2 * NEDGE) {
    e -= NEDGE;
    int pos = atomicAdd(&cur2[dst2[e]], 1);
    csr2[pos] = src2[e];
  }
}

// ---------------------------------------------------------------- fused per-graph chain
// One block = one (graph, side). 256 threads, 78336 B LDS -> 2 blocks/CU
// (verified: Occupancy 19.8%, VALUBusy 44%, 176 us). This round: W-chunk
// register prefetch (T14) -- next chunk's global loads issue before compute,
// so L2 latency hides under FMAs instead of inside the barrier pair.
__global__ __launch_bounds__(256, 2) void k_chain(
    const float* __restrict__ x1, const int* __restrict__ cent1, const float* __restrict__ rw1,
    const float* __restrict__ x2, const int* __restrict__ cent2, const float* __restrict__ rw2,
    const float* __restrict__ demb,
    const float* __restrict__ initW, const float* __restrict__ initb,
    const float* __restrict__ W1, const float* __restrict__ b1,
    const float* __restrict__ W2, const float* __restrict__ b2,
    const float* __restrict__ W3, const float* __restrict__ b3,
    const int* __restrict__ ofs1, const int* __restrict__ end1, const int* __restrict__ csr1,
    const int* __restrict__ ofs2, const int* __restrict__ end2, const int* __restrict__ csr2,
    const float* __restrict__ dinv1, const float* __restrict__ dinv2,
    float* __restrict__ feat1G, float* __restrict__ feat2G,
    float* __restrict__ f13G, float* __restrict__ f23G,
    float* __restrict__ gfs) {
  __shared__ float X[128 * 132];      // 67584 B: concat / feat / h (phase-shared)
  __shared__ float WcB[16 * 132];     // 8448 B: W chunk (16 k-rows) / pool tmp [8*128]
  __shared__ float dvL[128];
  __shared__ float bL[128];
  __shared__ int   oL[128], enL[128];

  const int t = threadIdx.x;
  const int side = blockIdx.x >> 8;
  const int g = blockIdx.x & 255;
  const int nb = g * NNODE;

  const float* xg    = side ? x2 : x1;
  const int*   centg = side ? cent2 : cent1;
  const float* rwg   = side ? rw2 : rw1;
  const int*   ofsg  = side ? ofs2 : ofs1;
  const int*   endg  = side ? end2 : end1;
  const int*   csrg  = side ? csr2 : csr1;
  const float* dinvg = side ? dinv2 : dinv1;
  float* featG = side ? feat2G : feat1G;
  float* f3G   = side ? f23G : f13G;

  // -------- phase -1: stage dinv / csr offsets / concat features into X
  const int e_base = ofsg[nb];
  if (t < 128) {
    dvL[t] = dinvg[nb + t];
    oL[t]  = ofsg[nb + t] - e_base;
    enL[t] = endg[nb + t] - e_base;
  }
  {
    int d = t >> 1, sub = t & 1;          // 2 threads per node, 34 cols each
    int node = nb + d;
    int ct = centg[node];
    const float* xr = xg + (size_t)node * LBL;
    const float* er = demb + ct * MAXDEG;
    const float* rr = rwg + (size_t)node * RWD;
    for (int c = sub * 34; c < sub * 34 + 34; ++c) {
      float v = 0.f;
      if (c < LBL) v = xr[c];
      else if (c < LBL + MAXDEG) v = er[c - LBL];
      else if (c < 61) v = rr[c - 45];
      X[d * 68 + c] = v;                  // concat overlay, stride 68
    }
  }
  __syncthreads();

  const int rg = t >> 3;           // row base; thread rows rg + 32*r
  const int jq = (t & 7) * 4;      // col quads jq + 32*q
  const int prow = t >> 5;         // W-stage row (with +8 for u=1)
  const int pc4  = (t & 31) * 4;   // W-stage col quad

  // -------- phase 0: feat = relu(concat @ initW + initb); write featG; pool 0
  {
    float acc[4][16] = {};
    float4 wpre[2];
#pragma unroll
    for (int u = 0; u < 2; ++u) {
      int gk = prow + 8 * u;
      wpre[u] = (gk < 61) ? *reinterpret_cast<const float4*>(&initW[(size_t)gk * FDIM + pc4])
                          : make_float4(0.f, 0.f, 0.f, 0.f);
    }
    for (int kc = 0; kc < 64; kc += 16) {
      __syncthreads();
#pragma unroll
      for (int u = 0; u < 2; ++u)
        *reinterpret_cast<float4*>(&WcB[(prow + 8 * u) * 132 + pc4]) = wpre[u];
      if (kc == 0 && t < 128) bL[t] = initb[t];
      if (kc + 16 < 64) {
#pragma unroll
        for (int u = 0; u < 2; ++u) {
          int gk = kc + 16 + prow + 8 * u;
          wpre[u] = (gk < 61) ? *reinterpret_cast<const float4*>(&initW[(size_t)gk * FDIM + pc4])
                              : make_float4(0.f, 0.f, 0.f, 0.f);
        }
      }
      __syncthreads();
      for (int kk = 0; kk < 16; kk += 4) {
        float av[4][4];
#pragma unroll
        for (int r = 0; r < 4; ++r) {
          float4 tmp = *reinterpret_cast<const float4*>(&X[(rg + 32 * r) * 68 + kc + kk]);
          av[r][0] = tmp.x; av[r][1] = tmp.y; av[r][2] = tmp.z; av[r][3] = tmp.w;
        }
#pragma unroll
        for (int c = 0; c < 4; ++c) {
          float4 w0 = *reinterpret_cast<const float4*>(&WcB[(kk + c) * 132 + jq]);
          float4 w1 = *reinterpret_cast<const float4*>(&WcB[(kk + c) * 132 + 32 + jq]);
          float4 w2 = *reinterpret_cast<const float4*>(&WcB[(kk + c) * 132 + 64 + jq]);
          float4 w3 = *reinterpret_cast<const float4*>(&WcB[(kk + c) * 132 + 96 + jq]);
#pragma unroll
          for (int r = 0; r < 4; ++r) {
            float a = av[r][c];
            acc[r][0]  += a * w0.x; acc[r][1]  += a * w0.y; acc[r][2]  += a * w0.z; acc[r][3]  += a * w0.w;
            acc[r][4]  += a * w1.x; acc[r][5]  += a * w1.y; acc[r][6]  += a * w1.z; acc[r][7]  += a * w1.w;
            acc[r][8]  += a * w2.x; acc[r][9]  += a * w2.y; acc[r][10] += a * w2.z; acc[r][11] += a * w2.w;
            acc[r][12] += a * w3.x; acc[r][13] += a * w3.y; acc[r][14] += a * w3.z; acc[r][15] += a * w3.w;
          }
        }
      }
    }
    __syncthreads();   // all concat reads done -> safe to overwrite X
#pragma unroll
    for (int r = 0; r < 4; ++r) {
      int row = rg + 32 * r;
#pragma unroll
      for (int q = 0; q < 4; ++q) {
        int col = q * 32 + jq;
        float4 bl = *reinterpret_cast<const float4*>(&bL[col]);
        float4 o = make_float4(fmaxf(acc[r][q * 4 + 0] + bl.x, 0.f),
                               fmaxf(acc[r][q * 4 + 1] + bl.y, 0.f),
                               fmaxf(acc[r][q * 4 + 2] + bl.z, 0.f),
                               fmaxf(acc[r][q * 4 + 3] + bl.w, 0.f));
        *reinterpret_cast<float4*>(&X[row * 132 + col]) = o;
        *reinterpret_cast<float4*>(&featG[(size_t)(nb + row) * FDIM + col]) = o;
      }
    }
    __syncthreads();
  }

  // -------- pool helper (256 threads: 8 row-groups x 16 rows)
#define POOL_LAYER(layer)                                                            \
  {                                                                                  \
    int j4 = (t & 31) * 4, qq = t >> 5;                                              \
    float4 pv = side ? make_float4(-INFINITY, -INFINITY, -INFINITY, -INFINITY)       \
                     : make_float4(0.f, 0.f, 0.f, 0.f);                              \
    for (int r = 0; r < 16; ++r) {                                                   \
      float4 fv = *reinterpret_cast<const float4*>(&X[(qq * 16 + r) * 132 + j4]);    \
      if (side) { pv.x = fmaxf(pv.x, fv.x); pv.y = fmaxf(pv.y, fv.y);                \
                  pv.z = fmaxf(pv.z, fv.z); pv.w = fmaxf(pv.w, fv.w); }              \
      else      { pv.x += fv.x; pv.y += fv.y; pv.z += fv.z; pv.w += fv.w; }          \
    }                                                                                \
    *reinterpret_cast<float4*>(&WcB[qq * 128 + j4]) = pv;                            \
    __syncthreads();                                                                 \
    if (t < 128) {                                                                   \
      float v = side ? -INFINITY : 0.f;                                              \
      for (int q2 = 0; q2 < 8; ++q2) {                                               \
        float w2 = WcB[q2 * 128 + t];                                                \
        v = side ? fmaxf(v, w2) : (v + w2);                                          \
      }                                                                              \
      gfs[g * 1024 + side * 512 + (layer) * 128 + t] = v;                            \
    }                                                                                \
  }

  POOL_LAYER(0)

  // -------- 3 conv layers
  for (int l = 0; l < 3; ++l) {
    const float* Wg = (l == 0) ? W1 : (l == 1) ? W2 : W3;   // SGPR select
    const float* bg = (l == 0) ? b1 : (l == 1) ? b2 : b3;
    // mm: h = (l>0 ? relu(X) : X) @ W_l   (acc in regs)
    float acc[4][16] = {};
    float4 wpre[2];
#pragma unroll
    for (int u = 0; u < 2; ++u)
      wpre[u] = *reinterpret_cast<const float4*>(&Wg[(size_t)(prow + 8 * u) * FDIM + pc4]);
    for (int kc = 0; kc < 128; kc += 16) {
      __syncthreads();   // protects WcB (pool tmp / prev chunk)
#pragma unroll
      for (int u = 0; u < 2; ++u)
        *reinterpret_cast<float4*>(&WcB[(prow + 8 * u) * 132 + pc4]) = wpre[u];
      if (kc == 0 && t < 128) bL[t] = bg[t];
      if (kc + 16 < 128) {
#pragma unroll
        for (int u = 0; u < 2; ++u)
          wpre[u] = *reinterpret_cast<const float4*>(&Wg[(size_t)(kc + 16 + prow + 8 * u) * FDIM + pc4]);
      }
      __syncthreads();
      for (int kk = 0; kk < 16; kk += 4) {
        float av[4][4];
#pragma unroll
        for (int r = 0; r < 4; ++r) {
          float4 tmp = *reinterpret_cast<const float4*>(&X[(rg + 32 * r) * 132 + kc + kk]);
          if (l > 0) {
            tmp.x = fmaxf(tmp.x, 0.f); tmp.y = fmaxf(tmp.y, 0.f);
            tmp.z = fmaxf(tmp.z, 0.f); tmp.w = fmaxf(tmp.w, 0.f);
          }
          av[r][0] = tmp.x; av[r][1] = tmp.y; av[r][2] = tmp.z; av[r][3] = tmp.w;
        }
#pragma unroll
        for (int c = 0; c < 4; ++c) {
          float4 w0 = *reinterpret_cast<const float4*>(&WcB[(kk + c) * 132 + jq]);
          float4 w1 = *reinterpret_cast<const float4*>(&WcB[(kk + c) * 132 + 32 + jq]);
          float4 w2 = *reinterpret_cast<const float4*>(&WcB[(kk + c) * 132 + 64 + jq]);
          float4 w3 = *reinterpret_cast<const float4*>(&WcB[(kk + c) * 132 + 96 + jq]);
#pragma unroll
          for (int r = 0; r < 4; ++r) {
            float a = av[r][c];
            acc[r][0]  += a * w0.x; acc[r][1]  += a * w0.y; acc[r][2]  += a * w0.z; acc[r][3]  += a * w0.w;
            acc[r][4]  += a * w1.x; acc[r][5]  += a * w1.y; acc[r][6]  += a * w1.z; acc[r][7]  += a * w1.w;
            acc[r][8]  += a * w2.x; acc[r][9]  += a * w2.y; acc[r][10] += a * w2.z; acc[r][11] += a * w2.w;
            acc[r][12] += a * w3.x; acc[r][13] += a * w3.y; acc[r][14] += a * w3.z; acc[r][15] += a * w3.w;
          }
        }
      }
    }
    __syncthreads();   // all reads of X(feat) done -> overwrite with h
#pragma unroll
    for (int r = 0; r < 4; ++r) {
      int row = rg + 32 * r;
#pragma unroll
      for (int q = 0; q < 4; ++q) {
        int col = q * 32 + jq;
        *reinterpret_cast<float4*>(&X[row * 132 + col]) =
            make_float4(acc[r][q * 4 + 0], acc[r][q * 4 + 1],
                        acc[r][q * 4 + 2], acc[r][q * 4 + 3]);
      }
    }
    __syncthreads();   // h complete

    // gather into regs: feat[d][f] = b[f] + dd*(dd*h[d][f] + sum_s dinv[s]*h[s][f])
    {
      int d = t >> 1, fc = (t & 1) * 64;   // 2 threads/node, 64 cols each
      float dd = dvL[d];
      float4 a[16];
#pragma unroll
      for (int u = 0; u < 16; ++u) {
        float4 hv = *reinterpret_cast<const float4*>(&X[d * 132 + fc + u * 4]);
        a[u] = make_float4(dd * hv.x, dd * hv.y, dd * hv.z, dd * hv.w);
      }
      int o0 = oL[d], o1 = enL[d];
      // prefetch-by-1 from L2-resident CSR
      int sj = (o0 < o1) ? (csrg[e_base + o0] - nb) : 0;
      for (int j = o0; j < o1; ++j) {
        int sn = (j + 1 < o1) ? (csrg[e_base + j + 1] - nb) : 0;
        float w = dvL[sj];
#pragma unroll
        for (int u = 0; u < 16; ++u) {
          float4 hv = *reinterpret_cast<const float4*>(&X[sj * 132 + fc + u * 4]);
          a[u].x += w * hv.x; a[u].y += w * hv.y; a[u].z += w * hv.z; a[u].w += w * hv.w;
        }
        sj = sn;
      }
      __syncthreads();   // all h reads done -> overwrite X with feat
#pragma unroll
      for (int u = 0; u < 16; ++u) {
        float4 bl = *reinterpret_cast<const float4*>(&bL[fc + u * 4]);
        float4 o = make_float4(bl.x + dd * a[u].x, bl.y + dd * a[u].y,
                               bl.z + dd * a[u].z, bl.w + dd * a[u].w);
        *reinterpret_cast<float4*>(&X[d * 132 + fc + u * 4]) = o;
        if (l == 2)
          *reinterpret_cast<float4*>(&f3G[(size_t)(nb + d) * FDIM + fc + u * 4]) = o;
      }
    }
    __syncthreads();   // feat complete

    POOL_LAYER(l + 1)
  }
#undef POOL_LAYER
}

// ---------------------------------------------------------------- fused sim: S = (F1@A)@F2^T -> sinkhorn
// One block = one (sim, graph): grid 512 covers both sims in one launch.
// F2 is stored TRANSPOSED in X2 at staging with a quad-rotation swizzle
// (logical col j of f-row c lives at phys ((j + (c&~3)) & 127)) so the
// S-phase reads its B-operand directly from X2: the per-chunk WcB transpose
// restage and its 16 barriers collapse to 1 barrier. Aaff chunks use the
// same register-prefetch as k_chain. FMA order unchanged -> bit-exact.
__global__ __launch_bounds__(1024) void k_sim(const float* __restrict__ F1s1,
                                              const float* __restrict__ F2s1,
                                              const float* __restrict__ F1s2,
                                              const float* __restrict__ F2s2,
                                              const float* __restrict__ Aaff,
                                              const int* __restrict__ topk,
                                              float* __restrict__ S1,
                                              float* __restrict__ S2) {
  __shared__ float X1[128 * 132];   // F1 -> Y (LDS-overwrite trick)
  __shared__ float X2[128 * 132];   // F2^T (swizzled)
  __shared__ float WcB[16 * 132];   // Aaff chunk
  __shared__ float rA[16], rB[16], bc[2];

  const int t = threadIdx.x;
  const int half = blockIdx.x >> 8;
  const int b = blockIdx.x & 255;
  const float* F1b = (half ? F1s2 : F1s1) + (size_t)b * NNODE * FDIM;
  const float* F2b = (half ? F2s2 : F2s1) + (size_t)b * NNODE * FDIM;
  float* Sout = (half ? S2 : S1) + (size_t)b * NNODE * NNODE;

  // -------- stage F1 row-major; F2 transposed+swizzled (coalesced reads)
#pragma unroll
  for (int p = 0; p < 4; ++p) {
    int fi = t + 1024 * p;            // float4 index 0..4095
    int row = fi >> 5, c4 = (fi & 31) * 4;
    *reinterpret_cast<float4*>(&X1[row * 132 + c4]) =
        *reinterpret_cast<const float4*>(&F1b[(size_t)row * FDIM + c4]);
    float4 v = *reinterpret_cast<const float4*>(&F2b[(size_t)row * FDIM + c4]);
    int ro = (row + c4) & 127;        // rot(c) = c&~3 = c4 for these 4 elems
    X2[(c4 + 0) * 132 + ro] = v.x;
    X2[(c4 + 1) * 132 + ro] = v.y;
    X2[(c4 + 2) * 132 + ro] = v.z;
    X2[(c4 + 3) * 132 + ro] = v.w;
  }

  const int rg = t >> 3;            // row 0..127
  const int jq = (t & 7) * 4;

  float acc[16];
#pragma unroll
  for (int u = 0; u < 16; ++u) acc[u] = 0.f;

  // -------- Y = F1 @ A   (A staged 16 k-rows at a time, reg-prefetched)
  float4 apre;
  if (t < 512) {
    int row = t >> 5, c4 = (t & 31) * 4;
    apre = *reinterpret_cast<const float4*>(&Aaff[(size_t)row * FDIM + c4]);
  }
  for (int kc = 0; kc < 128; kc += 16) {
    __syncthreads();                 // staging done (first iter) / WcB reads done
    if (t < 512) {
      int row = t >> 5, c4 = (t & 31) * 4;
      *reinterpret_cast<float4*>(&WcB[row * 132 + c4]) = apre;
      if (kc + 16 < 128)
        apre = *reinterpret_cast<const float4*>(&Aaff[(size_t)(kc + 16 + row) * FDIM + c4]);
    }
    __syncthreads();
    for (int kk = 0; kk < 16; kk += 4) {
      float4 a4 = *reinterpret_cast<const float4*>(&X1[rg * 132 + kc + kk]);
      float av[4] = {a4.x, a4.y, a4.z, a4.w};
#pragma unroll
      for (int c = 0; c < 4; ++c) {
        float4 w0 = *reinterpret_cast<const float4*>(&WcB[(kk + c) * 132 + jq]);
        float4 w1 = *reinterpret_cast<const float4*>(&WcB[(kk + c) * 132 + 32 + jq]);
        float4 w2 = *reinterpret_cast<const float4*>(&WcB[(kk + c) * 132 + 64 + jq]);
        float4 w3 = *reinterpret_cast<const float4*>(&WcB[(kk + c) * 132 + 96 + jq]);
        float a = av[c];
        acc[0]  += a * w0.x; acc[1]  += a * w0.y; acc[2]  += a * w0.z; acc[3]  += a * w0.w;
        acc[4]  += a * w1.x; acc[5]  += a * w1.y; acc[6]  += a * w1.z; acc[7]  += a * w1.w;
        acc[8]  += a * w2.x; acc[9]  += a * w2.y; acc[10] += a * w2.z; acc[11] += a * w2.w;
        acc[12] += a * w3.x; acc[13] += a * w3.y; acc[14] += a * w3.z; acc[15] += a * w3.w;
      }
    }
  }
  __syncthreads();                   // all F1 reads done -> overwrite X1 with Y
#pragma unroll
  for (int q = 0; q < 4; ++q)
    *reinterpret_cast<float4*>(&X1[rg * 132 + 32 * q + jq]) =
        make_float4(acc[q * 4 + 0], acc[q * 4 + 1], acc[q * 4 + 2], acc[q * 4 + 3]);

#pragma unroll
  for (int u = 0; u < 16; ++u) acc[u] = 0.f;
  __syncthreads();                   // Y visible; X2 ready -- no more barriers in S-phase

  // -------- S = Y @ F2^T  (B read directly from swizzled X2)
  for (int kc = 0; kc < 128; kc += 16) {
    for (int kk = 0; kk < 16; kk += 4) {
      float4 a4 = *reinterpret_cast<const float4*>(&X1[rg * 132 + kc + kk]);
      float av[4] = {a4.x, a4.y, a4.z, a4.w};
#pragma unroll
      for (int c = 0; c < 4; ++c) {
        int ck = kc + kk + c;
        const float* xb = &X2[ck * 132];
        int o0 = (jq + (ck & 124)) & 127;
        float4 w0 = *reinterpret_cast<const float4*>(&xb[o0]);
        float4 w1 = *reinterpret_cast<const float4*>(&xb[(o0 + 32) & 127]);
        float4 w2 = *reinterpret_cast<const float4*>(&xb[(o0 + 64) & 127]);
        float4 w3 = *reinterpret_cast<const float4*>(&xb[(o0 + 96) & 127]);
        float a = av[c];
        acc[0]  += a * w0.x; acc[1]  += a * w0.y; acc[2]  += a * w0.z; acc[3]  += a * w0.w;
        acc[4]  += a * w1.x; acc[5]  += a * w1.y; acc[6]  += a * w1.z; acc[7]  += a * w1.w;
        acc[8]  += a * w2.x; acc[9]  += a * w2.y; acc[10] += a * w2.z; acc[11] += a * w2.w;
        acc[12] += a * w3.x; acc[13] += a * w3.y; acc[14] += a * w3.z; acc[15] += a * w3.w;
      }
    }
  }

  // -------- sinkhorn on register-resident S (ownership-agnostic reductions)
  const int wave = t >> 6, lane = t & 63;
  {
    float mn = acc[0], mx = acc[0];
#pragma unroll
    for (int u = 1; u < 16; ++u) { mn = fminf(mn, acc[u]); mx = fmaxf(mx, acc[u]); }
    for (int off = 32; off; off >>= 1) {
      mn = fminf(mn, __shfl_down(mn, off));
      mx = fmaxf(mx, __shfl_down(mx, off));
    }
    if (lane == 0) { rA[wave] = mn; rB[wave] = mx; }
    __syncthreads();
    if (t < 16) {
      mn = rA[t]; mx = rB[t];
      for (int off = 8; off; off >>= 1) {
        mn = fminf(mn, __shfl_down(mn, off));
        mx = fmaxf(mx, __shfl_down(mx, off));
      }
      if (t == 0) { bc[0] = mn - 1.f; bc[1] = mx + 1.f; }
    }
    __syncthreads();
  }
  float a_lo = bc[0], a_hi = bc[1];

  float p[16], q[16];
#pragma unroll
  for (int u = 0; u < 16; ++u) {
    p[u] = __expf(a_lo - acc[u]);
    q[u] = __expf(acc[u] - a_hi);
  }

  const float Lf = (float)(NNODE * NNODE);
  float kt = 0.5f * (float)topk[0];

  float E0 = 1.f, E1 = 1.f, E0p = 1.f, E1p = 1.f;
  for (int it = 0; it < 6; ++it) {
    E0p = E0; E1p = E1;
    float r0 = 0.f, r1 = 0.f;
#pragma unroll
    for (int u = 0; u < 16; ++u) {
      float denom = fmaf(p[u], E0, q[u] * E1);
      float rin = __builtin_amdgcn_rcpf(denom);
      r0 = fmaf(p[u], rin, r0);
      r1 = fmaf(q[u], rin, r1);
    }
    for (int off = 32; off; off >>= 1) {
      r0 += __shfl_down(r0, off);
      r1 += __shfl_down(r1, off);
    }
    if (lane == 0) { rA[wave] = r0; rB[wave] = r1; }
    __syncthreads();
    if (t < 16) {
      r0 = rA[t]; r1 = rB[t];
      for (int off = 8; off; off >>= 1) {
        r0 += __shfl_down(r0, off);
        r1 += __shfl_down(r1, off);
      }
      if (t == 0) { bc[0] = (Lf - kt) / r0; bc[1] = kt / r1; }
    }
    __syncthreads();
    E0 = bc[0]; E1 = bc[1];
    __syncthreads();
  }

  // -------- final prob write (coalesced float4 per row)
  float* xrow = Sout + (size_t)rg * NNODE;
#pragma unroll
  for (int qd = 0; qd < 4; ++qd) {
    float o[4];
#pragma unroll
    for (int j = 0; j < 4; ++j) {
      int u = qd * 4 + j;
      float denom = fmaf(p[u], E0p, q[u] * E1p);
      o[j] = q[u] * E1 * __builtin_amdgcn_rcpf(denom);
    }
    *reinterpret_cast<float4*>(&xrow[32 * qd + jq]) = make_float4(o[0], o[1], o[2], o[3]);
  }
}

// ---------------------------------------------------------------- scoring MLP
__global__ __launch_bounds__(256) void k_mlp(const float* __restrict__ gfs,
                                             const float* __restrict__ W1,
                                             const float* __restrict__ b1,
                                             const float* __restrict__ W2,
                                             const float* __restrict__ b2,
                                             float* __restrict__ ged) {
  __shared__ float sm[1024];
  int b = blockIdx.x, t = threadIdx.x;
  const float* s = gfs + b * 1024;
#pragma unroll
  for (int qq = 0; qq < 4; ++qq) sm[t + 256 * qq] = s[t + 256 * qq];
  __syncthreads();
  int j4 = (t & 15) * 4, kp = t >> 4;
  float4 acc = make_float4(0.f, 0.f, 0.f, 0.f);
#pragma unroll 8
  for (int k = 0; k < 64; ++k) {
    float4 w = *reinterpret_cast<const float4*>(&W1[(size_t)(kp * 64 + k) * 64 + j4]);
    float sv = sm[kp * 64 + k];
    acc.x += sv * w.x; acc.y += sv * w.y; acc.z += sv * w.z; acc.w += sv * w.w;
  }
  __syncthreads();
  *reinterpret_cast<float4*>(&sm[kp * 64 + j4]) = acc;
  __syncthreads();
  if (t < 64) {
    float h = b1[t];
#pragma unroll
    for (int kp2 = 0; kp2 < 16; ++kp2) h += sm[kp2 * 64 + t];
    h = fmaxf(h, 0.f);
    float v = h * W2[t];
    for (int off = 32; off; off >>= 1) v += __shfl_down(v, off);
    if (t == 0) ged[b] = 1.f / (1.f + __expf(-(v + b2[0])));
  }
}

// ================================================================ launch
extern "C" void kernel_launch(void* const* d_in, const int* in_sizes, int n_in,
                              void* d_out, int out_size, void* d_ws, size_t ws_size,
                              hipStream_t stream) {
  (void)in_sizes; (void)n_in; (void)out_size; (void)ws_size;
  const float* x1    = (const float*)d_in[0];
  const int*   cent1 = (const int*)  d_in[1];
  const float* rw1   = (const float*)d_in[2];
  const int*   src1  = (const int*)  d_in[3];
  const int*   dst1  = (const int*)  d_in[4];
  const float* x2    = (const float*)d_in[5];
  const int*   cent2 = (const int*)  d_in[6];
  const float* rw2   = (const float*)d_in[7];
  const int*   src2  = (const int*)  d_in[8];
  const int*   dst2  = (const int*)  d_in[9];
  const float* demb  = (const float*)d_in[10];
  const float* initW = (const float*)d_in[11];
  const float* initb = (const float*)d_in[12];
  const float* W1    = (const float*)d_in[13];
  const float* b1    = (const float*)d_in[14];
  const float* W2    = (const float*)d_in[15];
  const float* b2    = (const float*)d_in[16];
  const float* W3    = (const float*)d_in[17];
  const float* b3    = (const float*)d_in[18];
  const float* Aaff  = (const float*)d_in[19];
  const float* scW1  = (const float*)d_in[20];
  const float* scb1  = (const float*)d_in[21];
  const float* scW2  = (const float*)d_in[22];
  const float* scb2  = (const float*)d_in[23];
  const int*   topk  = (const int*)  d_in[24];

  float* ws    = (float*)d_ws;
  float* feat1 = ws;
  float* feat2 = ws + (size_t)1 * NTF;
  float* f13   = ws + (size_t)2 * NTF;
  float* f23   = ws + (size_t)3 * NTF;
  float* dinv1 = ws + (size_t)4 * NTF;
  float* dinv2 = dinv1 + NT;
  float* gfs   = dinv2 + NT;

  float* ged = (float*)d_out;
  float* S1  = ged + BATCH;
  float* S2  = S1 + (size_t)BATCH * NNODE * NNODE;

  // int scratch lives in S1's output region (only written by k_sim AFTER chain)
  int* degi1 = (int*)S1;
  int* ofs1  = degi1 + NT;
  int* cur1  = ofs1 + NT;
  int* csr1  = cur1 + NT;
  int* degi2 = csr1 + NEDGE;
  int* ofs2  = degi2 + NT;
  int* cur2  = ofs2 + NT;
  int* csr2  = cur2 + NT;

  const int gE = NEDGE / 256;

  // CSR + degree norms (3 dispatches + 2 DMA memsets)
  hipMemsetAsync(degi1, 0, NT * sizeof(int), stream);
  hipMemsetAsync(degi2, 0, NT * sizeof(int), stream);
  k_deg2<<<2 * gE, 256, 0, stream>>>(dst1, dst2, degi1, degi2);
  k_scan2<<<2, 1024, 0, stream>>>(degi1, ofs1, cur1, dinv1, degi2, ofs2, cur2, dinv2);
  k_fill2<<<2 * gE, 256, 0, stream>>>(src1, dst1, cur1, csr1, src2, dst2, cur2, csr2);

  // fused conv chains (both sides), writes feat1/feat2/f13/f23/gfs
  k_chain<<<512, 256, 0, stream>>>(
      x1, cent1, rw1, x2, cent2, rw2, demb, initW, initb,
      W1, b1, W2, b2, W3, b3,
      ofs1, cur1, csr1, ofs2, cur2, csr2, dinv1, dinv2,
      feat1, feat2, f13, f23, gfs);

  // ged (only needs gfs; fills the gap right after chain)
  k_mlp<<<BATCH, 256, 0, stream>>>(gfs, scW1, scb1, scW2, scb2, ged);

  // both sims in one grid-512 launch
  k_sim<<<512, 1024, 0, stream>>>(feat1, feat2, f13, f23, Aaff, topk, S1, S2);
}

// Round 4
// 456.877 us; speedup vs baseline: 1.0249x; 1.0249x over previous
//
#include <hip/hip_runtime.h>
#include <math.h>

#define BATCH 256
#define NNODE 128
#define NT    32768      // BATCH*NNODE
#define FDIM  128
#define NEDGE 262144
#define LBL   29
#define MAXDEG 16
#define RWD   16
#define NTF   (NT * FDIM)

// ---------------------------------------------------------------- CSR build (side-fused)
__global__ void k_deg2(const int* __restrict__ dst1, const int* __restrict__ dst2,
                       int* __restrict__ d1, int* __restrict__ d2) {
  int e = blockIdx.x * 256 + threadIdx.x;
  if (e < NEDGE) atomicAdd(&d1[dst1[e]], 1);
  else if (e < 2 * NEDGE) atomicAdd(&d2[dst2[e - NEDGE]], 1);
}
// scan + dinv fused (scan already loads every degi value)
__global__ __launch_bounds__(1024) void k_scan2(const int* __restrict__ degi1,
                                                int* __restrict__ ofs1, int* __restrict__ cur1,
                                                float* __restrict__ dinv1,
                                                const int* __restrict__ degi2,
                                                int* __restrict__ ofs2, int* __restrict__ cur2,
                                                float* __restrict__ dinv2) {
  const int* degi = blockIdx.x ? degi2 : degi1;
  int* ofs   = blockIdx.x ? ofs2  : ofs1;
  int* cur   = blockIdx.x ? cur2  : cur1;
  float* dnv = blockIdx.x ? dinv2 : dinv1;
  __shared__ int part[1024];
  int t = threadIdx.x;
  int base = t * 32;
  int loc[32]; int sum = 0;
#pragma unroll
  for (int u = 0; u < 32; ++u) {
    int dg = degi[base + u];
    loc[u] = sum; sum += dg;
    dnv[base + u] = rsqrtf((float)(dg + 1));   // +1 self loop
  }
  part[t] = sum;
  __syncthreads();
  for (int off = 1; off < 1024; off <<= 1) {
    int v = (t >= off) ? part[t - off] : 0;
    __syncthreads();
    part[t] += v;
    __syncthreads();
  }
  int excl = (t == 0) ? 0 : part[t - 1];
#pragma unroll
  for (int u = 0; u < 32; ++u) {
    int o = excl + loc[u];
    ofs[base + u] = o; cur[base + u] = o;
  }
}
__global__ void k_fill2(const int* __restrict__ src1, const int* __restrict__ dst1,
                        int* __restrict__ cur1, int* __restrict__ csr1,
                        const int* __restrict__ src2, const int* __restrict__ dst2,
                        int* __restrict__ cur2, int* __restrict__ csr2) {
  int e = blockIdx.x * 256 + threadIdx.x;
  if (e < NEDGE) {
    int pos = atomicAdd(&cur1[dst1[e]], 1);
    csr1[pos] = src1[e];
  } else if (e < 2 * NEDGE) {
    e -= NEDGE;
    int pos = atomicAdd(&cur2[dst2[e]], 1);
    csr2[pos] = src2[e];
  }
}

// ---------------------------------------------------------------- fused per-graph chain
// One block = one (graph, side). 256 threads, 78336 B LDS -> 2 blocks/CU.
// EXACT R2 version (verified 175.5-176.5 us, FETCH 8.76 MB, VGPR 108).
// R3's W-prefetch REVERTED: it raised FETCH +24% and cost +4.4 us.
__global__ __launch_bounds__(256, 2) void k_chain(
    const float* __restrict__ x1, const int* __restrict__ cent1, const float* __restrict__ rw1,
    const float* __restrict__ x2, const int* __restrict__ cent2, const float* __restrict__ rw2,
    const float* __restrict__ demb,
    const float* __restrict__ initW, const float* __restrict__ initb,
    const float* __restrict__ W1, const float* __restrict__ b1,
    const float* __restrict__ W2, const float* __restrict__ b2,
    const float* __restrict__ W3, const float* __restrict__ b3,
    const int* __restrict__ ofs1, const int* __restrict__ end1, const int* __restrict__ csr1,
    const int* __restrict__ ofs2, const int* __restrict__ end2, const int* __restrict__ csr2,
    const float* __restrict__ dinv1, const float* __restrict__ dinv2,
    float* __restrict__ feat1G, float* __restrict__ feat2G,
    float* __restrict__ f13G, float* __restrict__ f23G,
    float* __restrict__ gfs) {
  __shared__ float X[128 * 132];      // 67584 B: concat / feat / h (phase-shared)
  __shared__ float WcB[16 * 132];     // 8448 B: W chunk (16 k-rows) / pool tmp [8*128]
  __shared__ float dvL[128];
  __shared__ float bL[128];
  __shared__ int   oL[128], enL[128];

  const int t = threadIdx.x;
  const int side = blockIdx.x >> 8;
  const int g = blockIdx.x & 255;
  const int nb = g * NNODE;

  const float* xg    = side ? x2 : x1;
  const int*   centg = side ? cent2 : cent1;
  const float* rwg   = side ? rw2 : rw1;
  const int*   ofsg  = side ? ofs2 : ofs1;
  const int*   endg  = side ? end2 : end1;
  const int*   csrg  = side ? csr2 : csr1;
  const float* dinvg = side ? dinv2 : dinv1;
  float* featG = side ? feat2G : feat1G;
  float* f3G   = side ? f23G : f13G;

  // -------- phase -1: stage dinv / csr offsets / concat features into X
  const int e_base = ofsg[nb];
  if (t < 128) {
    dvL[t] = dinvg[nb + t];
    oL[t]  = ofsg[nb + t] - e_base;
    enL[t] = endg[nb + t] - e_base;
  }
  {
    int d = t >> 1, sub = t & 1;          // 2 threads per node, 34 cols each
    int node = nb + d;
    int ct = centg[node];
    const float* xr = xg + (size_t)node * LBL;
    const float* er = demb + ct * MAXDEG;
    const float* rr = rwg + (size_t)node * RWD;
    for (int c = sub * 34; c < sub * 34 + 34; ++c) {
      float v = 0.f;
      if (c < LBL) v = xr[c];
      else if (c < LBL + MAXDEG) v = er[c - LBL];
      else if (c < 61) v = rr[c - 45];
      X[d * 68 + c] = v;                  // concat overlay, stride 68
    }
  }
  __syncthreads();

  const int rg = t >> 3;           // row base; thread rows rg + 32*r
  const int jq = (t & 7) * 4;      // col quads jq + 32*q

  // -------- phase 0: feat = relu(concat @ initW + initb); write featG; pool 0
  {
    float acc[4][16] = {};
    for (int kc = 0; kc < 64; kc += 16) {
      __syncthreads();
#pragma unroll
      for (int u = 0; u < 2; ++u) {
        int ll = t + 256 * u;                  // 0..511
        int row = ll >> 5, c4 = (ll & 31) * 4;
        int gk = kc + row;
        float4 w = (gk < 61) ? *reinterpret_cast<const float4*>(&initW[(size_t)gk * FDIM + c4])
                             : make_float4(0.f, 0.f, 0.f, 0.f);
        *reinterpret_cast<float4*>(&WcB[row * 132 + c4]) = w;
      }
      if (kc == 0 && t < 128) bL[t] = initb[t];
      __syncthreads();
      for (int kk = 0; kk < 16; kk += 4) {
        float av[4][4];
#pragma unroll
        for (int r = 0; r < 4; ++r) {
          float4 tmp = *reinterpret_cast<const float4*>(&X[(rg + 32 * r) * 68 + kc + kk]);
          av[r][0] = tmp.x; av[r][1] = tmp.y; av[r][2] = tmp.z; av[r][3] = tmp.w;
        }
#pragma unroll
        for (int c = 0; c < 4; ++c) {
          float4 w0 = *reinterpret_cast<const float4*>(&WcB[(kk + c) * 132 + jq]);
          float4 w1 = *reinterpret_cast<const float4*>(&WcB[(kk + c) * 132 + 32 + jq]);
          float4 w2 = *reinterpret_cast<const float4*>(&WcB[(kk + c) * 132 + 64 + jq]);
          float4 w3 = *reinterpret_cast<const float4*>(&WcB[(kk + c) * 132 + 96 + jq]);
#pragma unroll
          for (int r = 0; r < 4; ++r) {
            float a = av[r][c];
            acc[r][0]  += a * w0.x; acc[r][1]  += a * w0.y; acc[r][2]  += a * w0.z; acc[r][3]  += a * w0.w;
            acc[r][4]  += a * w1.x; acc[r][5]  += a * w1.y; acc[r][6]  += a * w1.z; acc[r][7]  += a * w1.w;
            acc[r][8]  += a * w2.x; acc[r][9]  += a * w2.y; acc[r][10] += a * w2.z; acc[r][11] += a * w2.w;
            acc[r][12] += a * w3.x; acc[r][13] += a * w3.y; acc[r][14] += a * w3.z; acc[r][15] += a * w3.w;
          }
        }
      }
    }
    __syncthreads();   // all concat reads done -> safe to overwrite X
#pragma unroll
    for (int r = 0; r < 4; ++r) {
      int row = rg + 32 * r;
#pragma unroll
      for (int q = 0; q < 4; ++q) {
        int col = q * 32 + jq;
        float4 bl = *reinterpret_cast<const float4*>(&bL[col]);
        float4 o = make_float4(fmaxf(acc[r][q * 4 + 0] + bl.x, 0.f),
                               fmaxf(acc[r][q * 4 + 1] + bl.y, 0.f),
                               fmaxf(acc[r][q * 4 + 2] + bl.z, 0.f),
                               fmaxf(acc[r][q * 4 + 3] + bl.w, 0.f));
        *reinterpret_cast<float4*>(&X[row * 132 + col]) = o;
        *reinterpret_cast<float4*>(&featG[(size_t)(nb + row) * FDIM + col]) = o;
      }
    }
    __syncthreads();
  }

  // -------- pool helper (256 threads: 8 row-groups x 16 rows)
#define POOL_LAYER(layer)                                                            \
  {                                                                                  \
    int j4 = (t & 31) * 4, qq = t >> 5;                                              \
    float4 pv = side ? make_float4(-INFINITY, -INFINITY, -INFINITY, -INFINITY)       \
                     : make_float4(0.f, 0.f, 0.f, 0.f);                              \
    for (int r = 0; r < 16; ++r) {                                                   \
      float4 fv = *reinterpret_cast<const float4*>(&X[(qq * 16 + r) * 132 + j4]);    \
      if (side) { pv.x = fmaxf(pv.x, fv.x); pv.y = fmaxf(pv.y, fv.y);                \
                  pv.z = fmaxf(pv.z, fv.z); pv.w = fmaxf(pv.w, fv.w); }              \
      else      { pv.x += fv.x; pv.y += fv.y; pv.z += fv.z; pv.w += fv.w; }          \
    }                                                                                \
    *reinterpret_cast<float4*>(&WcB[qq * 128 + j4]) = pv;                            \
    __syncthreads();                                                                 \
    if (t < 128) {                                                                   \
      float v = side ? -INFINITY : 0.f;                                              \
      for (int q2 = 0; q2 < 8; ++q2) {                                               \
        float w2 = WcB[q2 * 128 + t];                                                \
        v = side ? fmaxf(v, w2) : (v + w2);                                          \
      }                                                                              \
      gfs[g * 1024 + side * 512 + (layer) * 128 + t] = v;                            \
    }                                                                                \
  }

  POOL_LAYER(0)

  // -------- 3 conv layers
  for (int l = 0; l < 3; ++l) {
    const float* Wg = (l == 0) ? W1 : (l == 1) ? W2 : W3;   // SGPR select
    const float* bg = (l == 0) ? b1 : (l == 1) ? b2 : b3;
    // mm: h = (l>0 ? relu(X) : X) @ W_l   (acc in regs)
    float acc[4][16] = {};
    for (int kc = 0; kc < 128; kc += 16) {
      __syncthreads();   // protects WcB (pool tmp / prev chunk)
#pragma unroll
      for (int u = 0; u < 2; ++u) {
        int ll = t + 256 * u;
        int row = ll >> 5, c4 = (ll & 31) * 4;
        *reinterpret_cast<float4*>(&WcB[row * 132 + c4]) =
            *reinterpret_cast<const float4*>(&Wg[(size_t)(kc + row) * FDIM + c4]);
      }
      if (kc == 0 && t < 128) bL[t] = bg[t];
      __syncthreads();
      for (int kk = 0; kk < 16; kk += 4) {
        float av[4][4];
#pragma unroll
        for (int r = 0; r < 4; ++r) {
          float4 tmp = *reinterpret_cast<const float4*>(&X[(rg + 32 * r) * 132 + kc + kk]);
          if (l > 0) {
            tmp.x = fmaxf(tmp.x, 0.f); tmp.y = fmaxf(tmp.y, 0.f);
            tmp.z = fmaxf(tmp.z, 0.f); tmp.w = fmaxf(tmp.w, 0.f);
          }
          av[r][0] = tmp.x; av[r][1] = tmp.y; av[r][2] = tmp.z; av[r][3] = tmp.w;
        }
#pragma unroll
        for (int c = 0; c < 4; ++c) {
          float4 w0 = *reinterpret_cast<const float4*>(&WcB[(kk + c) * 132 + jq]);
          float4 w1 = *reinterpret_cast<const float4*>(&WcB[(kk + c) * 132 + 32 + jq]);
          float4 w2 = *reinterpret_cast<const float4*>(&WcB[(kk + c) * 132 + 64 + jq]);
          float4 w3 = *reinterpret_cast<const float4*>(&WcB[(kk + c) * 132 + 96 + jq]);
#pragma unroll
          for (int r = 0; r < 4; ++r) {
            float a = av[r][c];
            acc[r][0]  += a * w0.x; acc[r][1]  += a * w0.y; acc[r][2]  += a * w0.z; acc[r][3]  += a * w0.w;
            acc[r][4]  += a * w1.x; acc[r][5]  += a * w1.y; acc[r][6]  += a * w1.z; acc[r][7]  += a * w1.w;
            acc[r][8]  += a * w2.x; acc[r][9]  += a * w2.y; acc[r][10] += a * w2.z; acc[r][11] += a * w2.w;
            acc[r][12] += a * w3.x; acc[r][13] += a * w3.y; acc[r][14] += a * w3.z; acc[r][15] += a * w3.w;
          }
        }
      }
    }
    __syncthreads();   // all reads of X(feat) done -> overwrite with h
#pragma unroll
    for (int r = 0; r < 4; ++r) {
      int row = rg + 32 * r;
#pragma unroll
      for (int q = 0; q < 4; ++q) {
        int col = q * 32 + jq;
        *reinterpret_cast<float4*>(&X[row * 132 + col]) =
            make_float4(acc[r][q * 4 + 0], acc[r][q * 4 + 1],
                        acc[r][q * 4 + 2], acc[r][q * 4 + 3]);
      }
    }
    __syncthreads();   // h complete

    // gather into regs: feat[d][f] = b[f] + dd*(dd*h[d][f] + sum_s dinv[s]*h[s][f])
    {
      int d = t >> 1, fc = (t & 1) * 64;   // 2 threads/node, 64 cols each
      float dd = dvL[d];
      float4 a[16];
#pragma unroll
      for (int u = 0; u < 16; ++u) {
        float4 hv = *reinterpret_cast<const float4*>(&X[d * 132 + fc + u * 4]);
        a[u] = make_float4(dd * hv.x, dd * hv.y, dd * hv.z, dd * hv.w);
      }
      int o0 = oL[d], o1 = enL[d];
      // prefetch-by-1 from L2-resident CSR
      int sj = (o0 < o1) ? (csrg[e_base + o0] - nb) : 0;
      for (int j = o0; j < o1; ++j) {
        int sn = (j + 1 < o1) ? (csrg[e_base + j + 1] - nb) : 0;
        float w = dvL[sj];
#pragma unroll
        for (int u = 0; u < 16; ++u) {
          float4 hv = *reinterpret_cast<const float4*>(&X[sj * 132 + fc + u * 4]);
          a[u].x += w * hv.x; a[u].y += w * hv.y; a[u].z += w * hv.z; a[u].w += w * hv.w;
        }
        sj = sn;
      }
      __syncthreads();   // all h reads done -> overwrite X with feat
#pragma unroll
      for (int u = 0; u < 16; ++u) {
        float4 bl = *reinterpret_cast<const float4*>(&bL[fc + u * 4]);
        float4 o = make_float4(bl.x + dd * a[u].x, bl.y + dd * a[u].y,
                               bl.z + dd * a[u].z, bl.w + dd * a[u].w);
        *reinterpret_cast<float4*>(&X[d * 132 + fc + u * 4]) = o;
        if (l == 2)
          *reinterpret_cast<float4*>(&f3G[(size_t)(nb + d) * FDIM + fc + u * 4]) = o;
      }
    }
    __syncthreads();   // feat complete

    POOL_LAYER(l + 1)
  }
#undef POOL_LAYER
}

// ---------------------------------------------------------------- fused sim: S = (F1@A)@F2^T -> sinkhorn
// One block = one (sim, graph): grid 512 covers both sims in one launch.
// Inner body is the EXACT R2 version (verified): WcB per-chunk staging for
// both A and F2^T, plain (non-prefetched) loads. R3's X2-transpose swizzle
// and Aaff prefetch REVERTED (suspected +8 us).
__global__ __launch_bounds__(1024) void k_sim(const float* __restrict__ F1s1,
                                              const float* __restrict__ F2s1,
                                              const float* __restrict__ F1s2,
                                              const float* __restrict__ F2s2,
                                              const float* __restrict__ Aaff,
                                              const int* __restrict__ topk,
                                              float* __restrict__ S1,
                                              float* __restrict__ S2) {
  __shared__ float X1[128 * 132];   // F1 -> Y (LDS-overwrite trick)
  __shared__ float X2[128 * 132];   // F2
  __shared__ float WcB[16 * 132];   // A chunk / F2^T chunk
  __shared__ float rA[16], rB[16], bc[2];

  const int t = threadIdx.x;
  const int half = blockIdx.x >> 8;
  const int b = blockIdx.x & 255;
  const float* F1b = (half ? F1s2 : F1s1) + (size_t)b * NNODE * FDIM;
  const float* F2b = (half ? F2s2 : F2s1) + (size_t)b * NNODE * FDIM;
  float* Sout = (half ? S2 : S1) + (size_t)b * NNODE * NNODE;

  // -------- stage F1, F2 (coalesced)
#pragma unroll
  for (int p = 0; p < 4; ++p) {
    int fi = t + 1024 * p;            // float4 index 0..4095
    int row = fi >> 5, c4 = (fi & 31) * 4;
    *reinterpret_cast<float4*>(&X1[row * 132 + c4]) =
        *reinterpret_cast<const float4*>(&F1b[(size_t)row * FDIM + c4]);
    *reinterpret_cast<float4*>(&X2[row * 132 + c4]) =
        *reinterpret_cast<const float4*>(&F2b[(size_t)row * FDIM + c4]);
  }

  const int rg = t >> 3;            // row 0..127
  const int jq = (t & 7) * 4;

  float acc[16];
#pragma unroll
  for (int u = 0; u < 16; ++u) acc[u] = 0.f;

  // -------- Y = F1 @ A   (A staged 16 k-rows at a time)
  for (int kc = 0; kc < 128; kc += 16) {
    __syncthreads();                 // staging done (first iter) / WcB reads done
    if (t < 512) {
      int row = t >> 5, c4 = (t & 31) * 4;
      *reinterpret_cast<float4*>(&WcB[row * 132 + c4]) =
          *reinterpret_cast<const float4*>(&Aaff[(size_t)(kc + row) * FDIM + c4]);
    }
    __syncthreads();
    for (int kk = 0; kk < 16; kk += 4) {
      float4 a4 = *reinterpret_cast<const float4*>(&X1[rg * 132 + kc + kk]);
      float av[4] = {a4.x, a4.y, a4.z, a4.w};
#pragma unroll
      for (int c = 0; c < 4; ++c) {
        float4 w0 = *reinterpret_cast<const float4*>(&WcB[(kk + c) * 132 + jq]);
        float4 w1 = *reinterpret_cast<const float4*>(&WcB[(kk + c) * 132 + 32 + jq]);
        float4 w2 = *reinterpret_cast<const float4*>(&WcB[(kk + c) * 132 + 64 + jq]);
        float4 w3 = *reinterpret_cast<const float4*>(&WcB[(kk + c) * 132 + 96 + jq]);
        float a = av[c];
        acc[0]  += a * w0.x; acc[1]  += a * w0.y; acc[2]  += a * w0.z; acc[3]  += a * w0.w;
        acc[4]  += a * w1.x; acc[5]  += a * w1.y; acc[6]  += a * w1.z; acc[7]  += a * w1.w;
        acc[8]  += a * w2.x; acc[9]  += a * w2.y; acc[10] += a * w2.z; acc[11] += a * w2.w;
        acc[12] += a * w3.x; acc[13] += a * w3.y; acc[14] += a * w3.z; acc[15] += a * w3.w;
      }
    }
  }
  __syncthreads();                   // all F1 reads done -> overwrite X1 with Y
#pragma unroll
  for (int q = 0; q < 4; ++q)
    *reinterpret_cast<float4*>(&X1[rg * 132 + 32 * q + jq]) =
        make_float4(acc[q * 4 + 0], acc[q * 4 + 1], acc[q * 4 + 2], acc[q * 4 + 3]);

#pragma unroll
  for (int u = 0; u < 16; ++u) acc[u] = 0.f;

  // -------- S = Y @ F2^T  (F2^T chunks transposed through WcB)
  for (int kc = 0; kc < 128; kc += 16) {
    __syncthreads();                 // Y write visible (first iter) / WcB reads done
#pragma unroll
    for (int p = 0; p < 2; ++p) {
      int id = t + 1024 * p;         // 0..2047
      int kkr = id >> 7, c = id & 127;
      WcB[kkr * 132 + c] = X2[c * 132 + kc + kkr];
    }
    __syncthreads();
    for (int kk = 0; kk < 16; kk += 4) {
      float4 a4 = *reinterpret_cast<const float4*>(&X1[rg * 132 + kc + kk]);
      float av[4] = {a4.x, a4.y, a4.z, a4.w};
#pragma unroll
      for (int c = 0; c < 4; ++c) {
        float4 w0 = *reinterpret_cast<const float4*>(&WcB[(kk + c) * 132 + jq]);
        float4 w1 = *reinterpret_cast<const float4*>(&WcB[(kk + c) * 132 + 32 + jq]);
        float4 w2 = *reinterpret_cast<const float4*>(&WcB[(kk + c) * 132 + 64 + jq]);
        float4 w3 = *reinterpret_cast<const float4*>(&WcB[(kk + c) * 132 + 96 + jq]);
        float a = av[c];
        acc[0]  += a * w0.x; acc[1]  += a * w0.y; acc[2]  += a * w0.z; acc[3]  += a * w0.w;
        acc[4]  += a * w1.x; acc[5]  += a * w1.y; acc[6]  += a * w1.z; acc[7]  += a * w1.w;
        acc[8]  += a * w2.x; acc[9]  += a * w2.y; acc[10] += a * w2.z; acc[11] += a * w2.w;
        acc[12] += a * w3.x; acc[13] += a * w3.y; acc[14] += a * w3.z; acc[15] += a * w3.w;
      }
    }
  }

  // -------- sinkhorn on register-resident S (ownership-agnostic reductions)
  const int wave = t >> 6, lane = t & 63;
  {
    float mn = acc[0], mx = acc[0];
#pragma unroll
    for (int u = 1; u < 16; ++u) { mn = fminf(mn, acc[u]); mx = fmaxf(mx, acc[u]); }
    for (int off = 32; off; off >>= 1) {
      mn = fminf(mn, __shfl_down(mn, off));
      mx = fmaxf(mx, __shfl_down(mx, off));
    }
    if (lane == 0) { rA[wave] = mn; rB[wave] = mx; }
    __syncthreads();
    if (t < 16) {
      mn = rA[t]; mx = rB[t];
      for (int off = 8; off; off >>= 1) {
        mn = fminf(mn, __shfl_down(mn, off));
        mx = fmaxf(mx, __shfl_down(mx, off));
      }
      if (t == 0) { bc[0] = mn - 1.f; bc[1] = mx + 1.f; }
    }
    __syncthreads();
  }
  float a_lo = bc[0], a_hi = bc[1];

  float p[16], q[16];
#pragma unroll
  for (int u = 0; u < 16; ++u) {
    p[u] = __expf(a_lo - acc[u]);
    q[u] = __expf(acc[u] - a_hi);
  }

  const float Lf = (float)(NNODE * NNODE);
  float kt = 0.5f * (float)topk[0];

  float E0 = 1.f, E1 = 1.f, E0p = 1.f, E1p = 1.f;
  for (int it = 0; it < 6; ++it) {
    E0p = E0; E1p = E1;
    float r0 = 0.f, r1 = 0.f;
#pragma unroll
    for (int u = 0; u < 16; ++u) {
      float denom = fmaf(p[u], E0, q[u] * E1);
      float rin = __builtin_amdgcn_rcpf(denom);
      r0 = fmaf(p[u], rin, r0);
      r1 = fmaf(q[u], rin, r1);
    }
    for (int off = 32; off; off >>= 1) {
      r0 += __shfl_down(r0, off);
      r1 += __shfl_down(r1, off);
    }
    if (lane == 0) { rA[wave] = r0; rB[wave] = r1; }
    __syncthreads();
    if (t < 16) {
      r0 = rA[t]; r1 = rB[t];
      for (int off = 8; off; off >>= 1) {
        r0 += __shfl_down(r0, off);
        r1 += __shfl_down(r1, off);
      }
      if (t == 0) { bc[0] = (Lf - kt) / r0; bc[1] = kt / r1; }
    }
    __syncthreads();
    E0 = bc[0]; E1 = bc[1];
    __syncthreads();
  }

  // -------- final prob write (coalesced float4 per row)
  float* xrow = Sout + (size_t)rg * NNODE;
#pragma unroll
  for (int qd = 0; qd < 4; ++qd) {
    float o[4];
#pragma unroll
    for (int j = 0; j < 4; ++j) {
      int u = qd * 4 + j;
      float denom = fmaf(p[u], E0p, q[u] * E1p);
      o[j] = q[u] * E1 * __builtin_amdgcn_rcpf(denom);
    }
    *reinterpret_cast<float4*>(&xrow[32 * qd + jq]) = make_float4(o[0], o[1], o[2], o[3]);
  }
}

// ---------------------------------------------------------------- scoring MLP
__global__ __launch_bounds__(256) void k_mlp(const float* __restrict__ gfs,
                                             const float* __restrict__ W1,
                                             const float* __restrict__ b1,
                                             const float* __restrict__ W2,
                                             const float* __restrict__ b2,
                                             float* __restrict__ ged) {
  __shared__ float sm[1024];
  int b = blockIdx.x, t = threadIdx.x;
  const float* s = gfs + b * 1024;
#pragma unroll
  for (int qq = 0; qq < 4; ++qq) sm[t + 256 * qq] = s[t + 256 * qq];
  __syncthreads();
  int j4 = (t & 15) * 4, kp = t >> 4;
  float4 acc = make_float4(0.f, 0.f, 0.f, 0.f);
#pragma unroll 8
  for (int k = 0; k < 64; ++k) {
    float4 w = *reinterpret_cast<const float4*>(&W1[(size_t)(kp * 64 + k) * 64 + j4]);
    float sv = sm[kp * 64 + k];
    acc.x += sv * w.x; acc.y += sv * w.y; acc.z += sv * w.z; acc.w += sv * w.w;
  }
  __syncthreads();
  *reinterpret_cast<float4*>(&sm[kp * 64 + j4]) = acc;
  __syncthreads();
  if (t < 64) {
    float h = b1[t];
#pragma unroll
    for (int kp2 = 0; kp2 < 16; ++kp2) h += sm[kp2 * 64 + t];
    h = fmaxf(h, 0.f);
    float v = h * W2[t];
    for (int off = 32; off; off >>= 1) v += __shfl_down(v, off);
    if (t == 0) ged[b] = 1.f / (1.f + __expf(-(v + b2[0])));
  }
}

// ================================================================ launch
extern "C" void kernel_launch(void* const* d_in, const int* in_sizes, int n_in,
                              void* d_out, int out_size, void* d_ws, size_t ws_size,
                              hipStream_t stream) {
  (void)in_sizes; (void)n_in; (void)out_size; (void)ws_size;
  const float* x1    = (const float*)d_in[0];
  const int*   cent1 = (const int*)  d_in[1];
  const float* rw1   = (const float*)d_in[2];
  const int*   src1  = (const int*)  d_in[3];
  const int*   dst1  = (const int*)  d_in[4];
  const float* x2    = (const float*)d_in[5];
  const int*   cent2 = (const int*)  d_in[6];
  const float* rw2   = (const float*)d_in[7];
  const int*   src2  = (const int*)  d_in[8];
  const int*   dst2  = (const int*)  d_in[9];
  const float* demb  = (const float*)d_in[10];
  const float* initW = (const float*)d_in[11];
  const float* initb = (const float*)d_in[12];
  const float* W1    = (const float*)d_in[13];
  const float* b1    = (const float*)d_in[14];
  const float* W2    = (const float*)d_in[15];
  const float* b2    = (const float*)d_in[16];
  const float* W3    = (const float*)d_in[17];
  const float* b3    = (const float*)d_in[18];
  const float* Aaff  = (const float*)d_in[19];
  const float* scW1  = (const float*)d_in[20];
  const float* scb1  = (const float*)d_in[21];
  const float* scW2  = (const float*)d_in[22];
  const float* scb2  = (const float*)d_in[23];
  const int*   topk  = (const int*)  d_in[24];

  float* ws    = (float*)d_ws;
  float* feat1 = ws;
  float* feat2 = ws + (size_t)1 * NTF;
  float* f13   = ws + (size_t)2 * NTF;
  float* f23   = ws + (size_t)3 * NTF;
  float* dinv1 = ws + (size_t)4 * NTF;
  float* dinv2 = dinv1 + NT;
  float* gfs   = dinv2 + NT;

  float* ged = (float*)d_out;
  float* S1  = ged + BATCH;
  float* S2  = S1 + (size_t)BATCH * NNODE * NNODE;

  // int scratch lives in S1's output region (only written by k_sim AFTER chain)
  int* degi1 = (int*)S1;
  int* ofs1  = degi1 + NT;
  int* cur1  = ofs1 + NT;
  int* csr1  = cur1 + NT;
  int* degi2 = csr1 + NEDGE;
  int* ofs2  = degi2 + NT;
  int* cur2  = ofs2 + NT;
  int* csr2  = cur2 + NT;

  const int gE = NEDGE / 256;

  // CSR + degree norms (3 dispatches + 2 DMA memsets)
  hipMemsetAsync(degi1, 0, NT * sizeof(int), stream);
  hipMemsetAsync(degi2, 0, NT * sizeof(int), stream);
  k_deg2<<<2 * gE, 256, 0, stream>>>(dst1, dst2, degi1, degi2);
  k_scan2<<<2, 1024, 0, stream>>>(degi1, ofs1, cur1, dinv1, degi2, ofs2, cur2, dinv2);
  k_fill2<<<2 * gE, 256, 0, stream>>>(src1, dst1, cur1, csr1, src2, dst2, cur2, csr2);

  // fused conv chains (both sides), writes feat1/feat2/f13/f23/gfs
  k_chain<<<512, 256, 0, stream>>>(
      x1, cent1, rw1, x2, cent2, rw2, demb, initW, initb,
      W1, b1, W2, b2, W3, b3,
      ofs1, cur1, csr1, ofs2, cur2, csr2, dinv1, dinv2,
      feat1, feat2, f13, f23, gfs);

  // ged (only needs gfs; fills the gap right after chain)
  k_mlp<<<BATCH, 256, 0, stream>>>(gfs, scW1, scb1, scW2, scb2, ged);

  // both sims in one grid-512 launch
  k_sim<<<512, 1024, 0, stream>>>(feat1, feat2, f13, f23, Aaff, topk, S1, S2);
}

// Round 5
// 442.809 us; speedup vs baseline: 1.0574x; 1.0318x over previous
//
#include <hip/hip_runtime.h>
#include <math.h>

#define BATCH 256
#define NNODE 128
#define NT    32768      // BATCH*NNODE
#define FDIM  128
#define NEDGE 262144
#define LBL   29
#define MAXDEG 16
#define RWD   16
#define NTF   (NT * FDIM)

// ---------------------------------------------------------------- CSR build (side-fused)
__global__ void k_deg2(const int* __restrict__ dst1, const int* __restrict__ dst2,
                       int* __restrict__ d1, int* __restrict__ d2) {
  int e = blockIdx.x * 256 + threadIdx.x;
  if (e < NEDGE) atomicAdd(&d1[dst1[e]], 1);
  else if (e < 2 * NEDGE) atomicAdd(&d2[dst2[e - NEDGE]], 1);
}
// scan + dinv fused (scan already loads every degi value)
__global__ __launch_bounds__(1024) void k_scan2(const int* __restrict__ degi1,
                                                int* __restrict__ ofs1, int* __restrict__ cur1,
                                                float* __restrict__ dinv1,
                                                const int* __restrict__ degi2,
                                                int* __restrict__ ofs2, int* __restrict__ cur2,
                                                float* __restrict__ dinv2) {
  const int* degi = blockIdx.x ? degi2 : degi1;
  int* ofs   = blockIdx.x ? ofs2  : ofs1;
  int* cur   = blockIdx.x ? cur2  : cur1;
  float* dnv = blockIdx.x ? dinv2 : dinv1;
  __shared__ int part[1024];
  int t = threadIdx.x;
  int base = t * 32;
  int loc[32]; int sum = 0;
#pragma unroll
  for (int u = 0; u < 32; ++u) {
    int dg = degi[base + u];
    loc[u] = sum; sum += dg;
    dnv[base + u] = rsqrtf((float)(dg + 1));   // +1 self loop
  }
  part[t] = sum;
  __syncthreads();
  for (int off = 1; off < 1024; off <<= 1) {
    int v = (t >= off) ? part[t - off] : 0;
    __syncthreads();
    part[t] += v;
    __syncthreads();
  }
  int excl = (t == 0) ? 0 : part[t - 1];
#pragma unroll
  for (int u = 0; u < 32; ++u) {
    int o = excl + loc[u];
    ofs[base + u] = o; cur[base + u] = o;
  }
}
__global__ void k_fill2(const int* __restrict__ src1, const int* __restrict__ dst1,
                        int* __restrict__ cur1, int* __restrict__ csr1,
                        const int* __restrict__ src2, const int* __restrict__ dst2,
                        int* __restrict__ cur2, int* __restrict__ csr2) {
  int e = blockIdx.x * 256 + threadIdx.x;
  if (e < NEDGE) {
    int pos = atomicAdd(&cur1[dst1[e]], 1);
    csr1[pos] = src1[e];
  } else if (e < 2 * NEDGE) {
    e -= NEDGE;
    int pos = atomicAdd(&cur2[dst2[e]], 1);
    csr2[pos] = src2[e];
  }
}

// ---------------------------------------------------------------- fused per-graph chain
// One block = one (graph, side). 256 threads, 78336 B LDS -> 2 blocks/CU.
// EXACT R2/R4 version (verified 172.6-176.5 us, FETCH 8.76 MB, VGPR 108).
// Do not add W-prefetch (R3: +24% FETCH, +4.4 us).
__global__ __launch_bounds__(256, 2) void k_chain(
    const float* __restrict__ x1, const int* __restrict__ cent1, const float* __restrict__ rw1,
    const float* __restrict__ x2, const int* __restrict__ cent2, const float* __restrict__ rw2,
    const float* __restrict__ demb,
    const float* __restrict__ initW, const float* __restrict__ initb,
    const float* __restrict__ W1, const float* __restrict__ b1,
    const float* __restrict__ W2, const float* __restrict__ b2,
    const float* __restrict__ W3, const float* __restrict__ b3,
    const int* __restrict__ ofs1, const int* __restrict__ end1, const int* __restrict__ csr1,
    const int* __restrict__ ofs2, const int* __restrict__ end2, const int* __restrict__ csr2,
    const float* __restrict__ dinv1, const float* __restrict__ dinv2,
    float* __restrict__ feat1G, float* __restrict__ feat2G,
    float* __restrict__ f13G, float* __restrict__ f23G,
    float* __restrict__ gfs) {
  __shared__ float X[128 * 132];      // 67584 B: concat / feat / h (phase-shared)
  __shared__ float WcB[16 * 132];     // 8448 B: W chunk (16 k-rows) / pool tmp [8*128]
  __shared__ float dvL[128];
  __shared__ float bL[128];
  __shared__ int   oL[128], enL[128];

  const int t = threadIdx.x;
  const int side = blockIdx.x >> 8;
  const int g = blockIdx.x & 255;
  const int nb = g * NNODE;

  const float* xg    = side ? x2 : x1;
  const int*   centg = side ? cent2 : cent1;
  const float* rwg   = side ? rw2 : rw1;
  const int*   ofsg  = side ? ofs2 : ofs1;
  const int*   endg  = side ? end2 : end1;
  const int*   csrg  = side ? csr2 : csr1;
  const float* dinvg = side ? dinv2 : dinv1;
  float* featG = side ? feat2G : feat1G;
  float* f3G   = side ? f23G : f13G;

  // -------- phase -1: stage dinv / csr offsets / concat features into X
  const int e_base = ofsg[nb];
  if (t < 128) {
    dvL[t] = dinvg[nb + t];
    oL[t]  = ofsg[nb + t] - e_base;
    enL[t] = endg[nb + t] - e_base;
  }
  {
    int d = t >> 1, sub = t & 1;          // 2 threads per node, 34 cols each
    int node = nb + d;
    int ct = centg[node];
    const float* xr = xg + (size_t)node * LBL;
    const float* er = demb + ct * MAXDEG;
    const float* rr = rwg + (size_t)node * RWD;
    for (int c = sub * 34; c < sub * 34 + 34; ++c) {
      float v = 0.f;
      if (c < LBL) v = xr[c];
      else if (c < LBL + MAXDEG) v = er[c - LBL];
      else if (c < 61) v = rr[c - 45];
      X[d * 68 + c] = v;                  // concat overlay, stride 68
    }
  }
  __syncthreads();

  const int rg = t >> 3;           // row base; thread rows rg + 32*r
  const int jq = (t & 7) * 4;      // col quads jq + 32*q

  // -------- phase 0: feat = relu(concat @ initW + initb); write featG; pool 0
  {
    float acc[4][16] = {};
    for (int kc = 0; kc < 64; kc += 16) {
      __syncthreads();
#pragma unroll
      for (int u = 0; u < 2; ++u) {
        int ll = t + 256 * u;                  // 0..511
        int row = ll >> 5, c4 = (ll & 31) * 4;
        int gk = kc + row;
        float4 w = (gk < 61) ? *reinterpret_cast<const float4*>(&initW[(size_t)gk * FDIM + c4])
                             : make_float4(0.f, 0.f, 0.f, 0.f);
        *reinterpret_cast<float4*>(&WcB[row * 132 + c4]) = w;
      }
      if (kc == 0 && t < 128) bL[t] = initb[t];
      __syncthreads();
      for (int kk = 0; kk < 16; kk += 4) {
        float av[4][4];
#pragma unroll
        for (int r = 0; r < 4; ++r) {
          float4 tmp = *reinterpret_cast<const float4*>(&X[(rg + 32 * r) * 68 + kc + kk]);
          av[r][0] = tmp.x; av[r][1] = tmp.y; av[r][2] = tmp.z; av[r][3] = tmp.w;
        }
#pragma unroll
        for (int c = 0; c < 4; ++c) {
          float4 w0 = *reinterpret_cast<const float4*>(&WcB[(kk + c) * 132 + jq]);
          float4 w1 = *reinterpret_cast<const float4*>(&WcB[(kk + c) * 132 + 32 + jq]);
          float4 w2 = *reinterpret_cast<const float4*>(&WcB[(kk + c) * 132 + 64 + jq]);
          float4 w3 = *reinterpret_cast<const float4*>(&WcB[(kk + c) * 132 + 96 + jq]);
#pragma unroll
          for (int r = 0; r < 4; ++r) {
            float a = av[r][c];
            acc[r][0]  += a * w0.x; acc[r][1]  += a * w0.y; acc[r][2]  += a * w0.z; acc[r][3]  += a * w0.w;
            acc[r][4]  += a * w1.x; acc[r][5]  += a * w1.y; acc[r][6]  += a * w1.z; acc[r][7]  += a * w1.w;
            acc[r][8]  += a * w2.x; acc[r][9]  += a * w2.y; acc[r][10] += a * w2.z; acc[r][11] += a * w2.w;
            acc[r][12] += a * w3.x; acc[r][13] += a * w3.y; acc[r][14] += a * w3.z; acc[r][15] += a * w3.w;
          }
        }
      }
    }
    __syncthreads();   // all concat reads done -> safe to overwrite X
#pragma unroll
    for (int r = 0; r < 4; ++r) {
      int row = rg + 32 * r;
#pragma unroll
      for (int q = 0; q < 4; ++q) {
        int col = q * 32 + jq;
        float4 bl = *reinterpret_cast<const float4*>(&bL[col]);
        float4 o = make_float4(fmaxf(acc[r][q * 4 + 0] + bl.x, 0.f),
                               fmaxf(acc[r][q * 4 + 1] + bl.y, 0.f),
                               fmaxf(acc[r][q * 4 + 2] + bl.z, 0.f),
                               fmaxf(acc[r][q * 4 + 3] + bl.w, 0.f));
        *reinterpret_cast<float4*>(&X[row * 132 + col]) = o;
        *reinterpret_cast<float4*>(&featG[(size_t)(nb + row) * FDIM + col]) = o;
      }
    }
    __syncthreads();
  }

  // -------- pool helper (256 threads: 8 row-groups x 16 rows)
#define POOL_LAYER(layer)                                                            \
  {                                                                                  \
    int j4 = (t & 31) * 4, qq = t >> 5;                                              \
    float4 pv = side ? make_float4(-INFINITY, -INFINITY, -INFINITY, -INFINITY)       \
                     : make_float4(0.f, 0.f, 0.f, 0.f);                              \
    for (int r = 0; r < 16; ++r) {                                                   \
      float4 fv = *reinterpret_cast<const float4*>(&X[(qq * 16 + r) * 132 + j4]);    \
      if (side) { pv.x = fmaxf(pv.x, fv.x); pv.y = fmaxf(pv.y, fv.y);                \
                  pv.z = fmaxf(pv.z, fv.z); pv.w = fmaxf(pv.w, fv.w); }              \
      else      { pv.x += fv.x; pv.y += fv.y; pv.z += fv.z; pv.w += fv.w; }          \
    }                                                                                \
    *reinterpret_cast<float4*>(&WcB[qq * 128 + j4]) = pv;                            \
    __syncthreads();                                                                 \
    if (t < 128) {                                                                   \
      float v = side ? -INFINITY : 0.f;                                              \
      for (int q2 = 0; q2 < 8; ++q2) {                                               \
        float w2 = WcB[q2 * 128 + t];                                                \
        v = side ? fmaxf(v, w2) : (v + w2);                                          \
      }                                                                              \
      gfs[g * 1024 + side * 512 + (layer) * 128 + t] = v;                            \
    }                                                                                \
  }

  POOL_LAYER(0)

  // -------- 3 conv layers
  for (int l = 0; l < 3; ++l) {
    const float* Wg = (l == 0) ? W1 : (l == 1) ? W2 : W3;   // SGPR select
    const float* bg = (l == 0) ? b1 : (l == 1) ? b2 : b3;
    // mm: h = (l>0 ? relu(X) : X) @ W_l   (acc in regs)
    float acc[4][16] = {};
    for (int kc = 0; kc < 128; kc += 16) {
      __syncthreads();   // protects WcB (pool tmp / prev chunk)
#pragma unroll
      for (int u = 0; u < 2; ++u) {
        int ll = t + 256 * u;
        int row = ll >> 5, c4 = (ll & 31) * 4;
        *reinterpret_cast<float4*>(&WcB[row * 132 + c4]) =
            *reinterpret_cast<const float4*>(&Wg[(size_t)(kc + row) * FDIM + c4]);
      }
      if (kc == 0 && t < 128) bL[t] = bg[t];
      __syncthreads();
      for (int kk = 0; kk < 16; kk += 4) {
        float av[4][4];
#pragma unroll
        for (int r = 0; r < 4; ++r) {
          float4 tmp = *reinterpret_cast<const float4*>(&X[(rg + 32 * r) * 132 + kc + kk]);
          if (l > 0) {
            tmp.x = fmaxf(tmp.x, 0.f); tmp.y = fmaxf(tmp.y, 0.f);
            tmp.z = fmaxf(tmp.z, 0.f); tmp.w = fmaxf(tmp.w, 0.f);
          }
          av[r][0] = tmp.x; av[r][1] = tmp.y; av[r][2] = tmp.z; av[r][3] = tmp.w;
        }
#pragma unroll
        for (int c = 0; c < 4; ++c) {
          float4 w0 = *reinterpret_cast<const float4*>(&WcB[(kk + c) * 132 + jq]);
          float4 w1 = *reinterpret_cast<const float4*>(&WcB[(kk + c) * 132 + 32 + jq]);
          float4 w2 = *reinterpret_cast<const float4*>(&WcB[(kk + c) * 132 + 64 + jq]);
          float4 w3 = *reinterpret_cast<const float4*>(&WcB[(kk + c) * 132 + 96 + jq]);
#pragma unroll
          for (int r = 0; r < 4; ++r) {
            float a = av[r][c];
            acc[r][0]  += a * w0.x; acc[r][1]  += a * w0.y; acc[r][2]  += a * w0.z; acc[r][3]  += a * w0.w;
            acc[r][4]  += a * w1.x; acc[r][5]  += a * w1.y; acc[r][6]  += a * w1.z; acc[r][7]  += a * w1.w;
            acc[r][8]  += a * w2.x; acc[r][9]  += a * w2.y; acc[r][10] += a * w2.z; acc[r][11] += a * w2.w;
            acc[r][12] += a * w3.x; acc[r][13] += a * w3.y; acc[r][14] += a * w3.z; acc[r][15] += a * w3.w;
          }
        }
      }
    }
    __syncthreads();   // all reads of X(feat) done -> overwrite with h
#pragma unroll
    for (int r = 0; r < 4; ++r) {
      int row = rg + 32 * r;
#pragma unroll
      for (int q = 0; q < 4; ++q) {
        int col = q * 32 + jq;
        *reinterpret_cast<float4*>(&X[row * 132 + col]) =
            make_float4(acc[r][q * 4 + 0], acc[r][q * 4 + 1],
                        acc[r][q * 4 + 2], acc[r][q * 4 + 3]);
      }
    }
    __syncthreads();   // h complete

    // gather into regs: feat[d][f] = b[f] + dd*(dd*h[d][f] + sum_s dinv[s]*h[s][f])
    {
      int d = t >> 1, fc = (t & 1) * 64;   // 2 threads/node, 64 cols each
      float dd = dvL[d];
      float4 a[16];
#pragma unroll
      for (int u = 0; u < 16; ++u) {
        float4 hv = *reinterpret_cast<const float4*>(&X[d * 132 + fc + u * 4]);
        a[u] = make_float4(dd * hv.x, dd * hv.y, dd * hv.z, dd * hv.w);
      }
      int o0 = oL[d], o1 = enL[d];
      // prefetch-by-1 from L2-resident CSR
      int sj = (o0 < o1) ? (csrg[e_base + o0] - nb) : 0;
      for (int j = o0; j < o1; ++j) {
        int sn = (j + 1 < o1) ? (csrg[e_base + j + 1] - nb) : 0;
        float w = dvL[sj];
#pragma unroll
        for (int u = 0; u < 16; ++u) {
          float4 hv = *reinterpret_cast<const float4*>(&X[sj * 132 + fc + u * 4]);
          a[u].x += w * hv.x; a[u].y += w * hv.y; a[u].z += w * hv.z; a[u].w += w * hv.w;
        }
        sj = sn;
      }
      __syncthreads();   // all h reads done -> overwrite X with feat
#pragma unroll
      for (int u = 0; u < 16; ++u) {
        float4 bl = *reinterpret_cast<const float4*>(&bL[fc + u * 4]);
        float4 o = make_float4(bl.x + dd * a[u].x, bl.y + dd * a[u].y,
                               bl.z + dd * a[u].z, bl.w + dd * a[u].w);
        *reinterpret_cast<float4*>(&X[d * 132 + fc + u * 4]) = o;
        if (l == 2)
          *reinterpret_cast<float4*>(&f3G[(size_t)(nb + d) * FDIM + fc + u * 4]) = o;
      }
    }
    __syncthreads();   // feat complete

    POOL_LAYER(l + 1)
  }
#undef POOL_LAYER
}

// ---------------------------------------------------------------- fused sim: S = (F1@A)@F2^T -> sinkhorn
// One block = one (sim, graph): grid 512 covers both sims in one launch.
// RESTRUCTURED (this round): near-zero barriers in the matmul phases.
//  * X1 holds the FULL Aaff (64 KB, staged once) -> Y-phase has no per-chunk
//    staging and no barriers; the A-operand row F1[rg] is read directly from
//    global (L3-resident, 8-thread row-sharing).
//  * X2 holds F2 TRANSPOSED (k-major), built once at staging time (scattered
//    one-time writes, ~4-way conflict) -> S-phase reads B directly, zero
//    barriers, no per-chunk WcB transpose.
//  * Y overwrites X1 between one barrier pair (proven LDS-overwrite trick).
// k-summation strictly ascending in both phases -> bit-exact vs R4.
__global__ __launch_bounds__(1024) void k_sim(const float* __restrict__ F1s1,
                                              const float* __restrict__ F2s1,
                                              const float* __restrict__ F1s2,
                                              const float* __restrict__ F2s2,
                                              const float* __restrict__ Aaff,
                                              const int* __restrict__ topk,
                                              float* __restrict__ S1,
                                              float* __restrict__ S2) {
  __shared__ float X1[128 * 132];   // Aaff -> Y (LDS-overwrite trick)
  __shared__ float X2[128 * 132];   // F2^T (k-major)
  __shared__ float rA[16], rB[16], bc[2];

  const int t = threadIdx.x;
  const int half = blockIdx.x >> 8;
  const int b = blockIdx.x & 255;
  const float* F1b = (half ? F1s2 : F1s1) + (size_t)b * NNODE * FDIM;
  const float* F2b = (half ? F2s2 : F2s1) + (size_t)b * NNODE * FDIM;
  float* Sout = (half ? S2 : S1) + (size_t)b * NNODE * NNODE;

  // -------- stage Aaff row-major into X1 (coalesced, conflict-free)
#pragma unroll
  for (int p = 0; p < 4; ++p) {
    int fi = t + 1024 * p;            // float4 index 0..4095
    int row = fi >> 5, c4 = (fi & 31) * 4;
    *reinterpret_cast<float4*>(&X1[row * 132 + c4]) =
        *reinterpret_cast<const float4*>(&Aaff[(size_t)row * FDIM + c4]);
  }
  // -------- stage F2 transposed into X2 (one-time scattered writes, ~4-way)
  {
    int row = t >> 3;                 // 0..127 (all rows covered per p)
    int cq  = (t & 7) * 4;
#pragma unroll
    for (int p = 0; p < 4; ++p) {
      int c4 = p * 32 + cq;
      float4 v = *reinterpret_cast<const float4*>(&F2b[(size_t)row * FDIM + c4]);
      X2[(c4 + 0) * 132 + row] = v.x;
      X2[(c4 + 1) * 132 + row] = v.y;
      X2[(c4 + 2) * 132 + row] = v.z;
      X2[(c4 + 3) * 132 + row] = v.w;
    }
  }
  __syncthreads();

  const int rg = t >> 3;            // output row 0..127
  const int jq = (t & 7) * 4;
  const float* f1row = F1b + (size_t)rg * FDIM;

  float acc[16];
#pragma unroll
  for (int u = 0; u < 16; ++u) acc[u] = 0.f;

  // -------- Y = F1 @ A : av from global (L3), w from X1; no barriers
  for (int k0 = 0; k0 < 128; k0 += 4) {
    float4 a4 = *reinterpret_cast<const float4*>(&f1row[k0]);
    float av[4] = {a4.x, a4.y, a4.z, a4.w};
#pragma unroll
    for (int c = 0; c < 4; ++c) {
      const float* wb = &X1[(k0 + c) * 132];
      float4 w0 = *reinterpret_cast<const float4*>(&wb[jq]);
      float4 w1 = *reinterpret_cast<const float4*>(&wb[32 + jq]);
      float4 w2 = *reinterpret_cast<const float4*>(&wb[64 + jq]);
      float4 w3 = *reinterpret_cast<const float4*>(&wb[96 + jq]);
      float a = av[c];
      acc[0]  += a * w0.x; acc[1]  += a * w0.y; acc[2]  += a * w0.z; acc[3]  += a * w0.w;
      acc[4]  += a * w1.x; acc[5]  += a * w1.y; acc[6]  += a * w1.z; acc[7]  += a * w1.w;
      acc[8]  += a * w2.x; acc[9]  += a * w2.y; acc[10] += a * w2.z; acc[11] += a * w2.w;
      acc[12] += a * w3.x; acc[13] += a * w3.y; acc[14] += a * w3.z; acc[15] += a * w3.w;
    }
  }
  __syncthreads();                   // all A reads done -> overwrite X1 with Y
#pragma unroll
  for (int q = 0; q < 4; ++q)
    *reinterpret_cast<float4*>(&X1[rg * 132 + 32 * q + jq]) =
        make_float4(acc[q * 4 + 0], acc[q * 4 + 1], acc[q * 4 + 2], acc[q * 4 + 3]);

#pragma unroll
  for (int u = 0; u < 16; ++u) acc[u] = 0.f;
  __syncthreads();                   // Y visible; S-phase barrier-free

  // -------- S = Y @ F2^T : both operands LDS-resident, no barriers
  for (int k0 = 0; k0 < 128; k0 += 4) {
    float4 a4 = *reinterpret_cast<const float4*>(&X1[rg * 132 + k0]);
    float av[4] = {a4.x, a4.y, a4.z, a4.w};
#pragma unroll
    for (int c = 0; c < 4; ++c) {
      const float* wb = &X2[(k0 + c) * 132];
      float4 w0 = *reinterpret_cast<const float4*>(&wb[jq]);
      float4 w1 = *reinterpret_cast<const float4*>(&wb[32 + jq]);
      float4 w2 = *reinterpret_cast<const float4*>(&wb[64 + jq]);
      float4 w3 = *reinterpret_cast<const float4*>(&wb[96 + jq]);
      float a = av[c];
      acc[0]  += a * w0.x; acc[1]  += a * w0.y; acc[2]  += a * w0.z; acc[3]  += a * w0.w;
      acc[4]  += a * w1.x; acc[5]  += a * w1.y; acc[6]  += a * w1.z; acc[7]  += a * w1.w;
      acc[8]  += a * w2.x; acc[9]  += a * w2.y; acc[10] += a * w2.z; acc[11] += a * w2.w;
      acc[12] += a * w3.x; acc[13] += a * w3.y; acc[14] += a * w3.z; acc[15] += a * w3.w;
    }
  }

  // -------- sinkhorn on register-resident S (ownership-agnostic reductions)
  const int wave = t >> 6, lane = t & 63;
  {
    float mn = acc[0], mx = acc[0];
#pragma unroll
    for (int u = 1; u < 16; ++u) { mn = fminf(mn, acc[u]); mx = fmaxf(mx, acc[u]); }
    for (int off = 32; off; off >>= 1) {
      mn = fminf(mn, __shfl_down(mn, off));
      mx = fmaxf(mx, __shfl_down(mx, off));
    }
    if (lane == 0) { rA[wave] = mn; rB[wave] = mx; }
    __syncthreads();
    if (t < 16) {
      mn = rA[t]; mx = rB[t];
      for (int off = 8; off; off >>= 1) {
        mn = fminf(mn, __shfl_down(mn, off));
        mx = fmaxf(mx, __shfl_down(mx, off));
      }
      if (t == 0) { bc[0] = mn - 1.f; bc[1] = mx + 1.f; }
    }
    __syncthreads();
  }
  float a_lo = bc[0], a_hi = bc[1];

  float p[16], q[16];
#pragma unroll
  for (int u = 0; u < 16; ++u) {
    p[u] = __expf(a_lo - acc[u]);
    q[u] = __expf(acc[u] - a_hi);
  }

  const float Lf = (float)(NNODE * NNODE);
  float kt = 0.5f * (float)topk[0];

  float E0 = 1.f, E1 = 1.f, E0p = 1.f, E1p = 1.f;
  for (int it = 0; it < 6; ++it) {
    E0p = E0; E1p = E1;
    float r0 = 0.f, r1 = 0.f;
#pragma unroll
    for (int u = 0; u < 16; ++u) {
      float denom = fmaf(p[u], E0, q[u] * E1);
      float rin = __builtin_amdgcn_rcpf(denom);
      r0 = fmaf(p[u], rin, r0);
      r1 = fmaf(q[u], rin, r1);
    }
    for (int off = 32; off; off >>= 1) {
      r0 += __shfl_down(r0, off);
      r1 += __shfl_down(r1, off);
    }
    if (lane == 0) { rA[wave] = r0; rB[wave] = r1; }
    __syncthreads();
    if (t < 16) {
      r0 = rA[t]; r1 = rB[t];
      for (int off = 8; off; off >>= 1) {
        r0 += __shfl_down(r0, off);
        r1 += __shfl_down(r1, off);
      }
      if (t == 0) { bc[0] = (Lf - kt) / r0; bc[1] = kt / r1; }
    }
    __syncthreads();
    E0 = bc[0]; E1 = bc[1];
    __syncthreads();
  }

  // -------- final prob write (coalesced float4 per row)
  float* xrow = Sout + (size_t)rg * NNODE;
#pragma unroll
  for (int qd = 0; qd < 4; ++qd) {
    float o[4];
#pragma unroll
    for (int j = 0; j < 4; ++j) {
      int u = qd * 4 + j;
      float denom = fmaf(p[u], E0p, q[u] * E1p);
      o[j] = q[u] * E1 * __builtin_amdgcn_rcpf(denom);
    }
    *reinterpret_cast<float4*>(&xrow[32 * qd + jq]) = make_float4(o[0], o[1], o[2], o[3]);
  }
}

// ---------------------------------------------------------------- scoring MLP
__global__ __launch_bounds__(256) void k_mlp(const float* __restrict__ gfs,
                                             const float* __restrict__ W1,
                                             const float* __restrict__ b1,
                                             const float* __restrict__ W2,
                                             const float* __restrict__ b2,
                                             float* __restrict__ ged) {
  __shared__ float sm[1024];
  int b = blockIdx.x, t = threadIdx.x;
  const float* s = gfs + b * 1024;
#pragma unroll
  for (int qq = 0; qq < 4; ++qq) sm[t + 256 * qq] = s[t + 256 * qq];
  __syncthreads();
  int j4 = (t & 15) * 4, kp = t >> 4;
  float4 acc = make_float4(0.f, 0.f, 0.f, 0.f);
#pragma unroll 8
  for (int k = 0; k < 64; ++k) {
    float4 w = *reinterpret_cast<const float4*>(&W1[(size_t)(kp * 64 + k) * 64 + j4]);
    float sv = sm[kp * 64 + k];
    acc.x += sv * w.x; acc.y += sv * w.y; acc.z += sv * w.z; acc.w += sv * w.w;
  }
  __syncthreads();
  *reinterpret_cast<float4*>(&sm[kp * 64 + j4]) = acc;
  __syncthreads();
  if (t < 64) {
    float h = b1[t];
#pragma unroll
    for (int kp2 = 0; kp2 < 16; ++kp2) h += sm[kp2 * 64 + t];
    h = fmaxf(h, 0.f);
    float v = h * W2[t];
    for (int off = 32; off; off >>= 1) v += __shfl_down(v, off);
    if (t == 0) ged[b] = 1.f / (1.f + __expf(-(v + b2[0])));
  }
}

// ================================================================ launch
extern "C" void kernel_launch(void* const* d_in, const int* in_sizes, int n_in,
                              void* d_out, int out_size, void* d_ws, size_t ws_size,
                              hipStream_t stream) {
  (void)in_sizes; (void)n_in; (void)out_size; (void)ws_size;
  const float* x1    = (const float*)d_in[0];
  const int*   cent1 = (const int*)  d_in[1];
  const float* rw1   = (const float*)d_in[2];
  const int*   src1  = (const int*)  d_in[3];
  const int*   dst1  = (const int*)  d_in[4];
  const float* x2    = (const float*)d_in[5];
  const int*   cent2 = (const int*)  d_in[6];
  const float* rw2   = (const float*)d_in[7];
  const int*   src2  = (const int*)  d_in[8];
  const int*   dst2  = (const int*)  d_in[9];
  const float* demb  = (const float*)d_in[10];
  const float* initW = (const float*)d_in[11];
  const float* initb = (const float*)d_in[12];
  const float* W1    = (const float*)d_in[13];
  const float* b1    = (const float*)d_in[14];
  const float* W2    = (const float*)d_in[15];
  const float* b2    = (const float*)d_in[16];
  const float* W3    = (const float*)d_in[17];
  const float* b3    = (const float*)d_in[18];
  const float* Aaff  = (const float*)d_in[19];
  const float* scW1  = (const float*)d_in[20];
  const float* scb1  = (const float*)d_in[21];
  const float* scW2  = (const float*)d_in[22];
  const float* scb2  = (const float*)d_in[23];
  const int*   topk  = (const int*)  d_in[24];

  float* ws    = (float*)d_ws;
  float* feat1 = ws;
  float* feat2 = ws + (size_t)1 * NTF;
  float* f13   = ws + (size_t)2 * NTF;
  float* f23   = ws + (size_t)3 * NTF;
  float* dinv1 = ws + (size_t)4 * NTF;
  float* dinv2 = dinv1 + NT;
  float* gfs   = dinv2 + NT;

  float* ged = (float*)d_out;
  float* S1  = ged + BATCH;
  float* S2  = S1 + (size_t)BATCH * NNODE * NNODE;

  // int scratch lives in S1's output region (only written by k_sim AFTER chain)
  int* degi1 = (int*)S1;
  int* ofs1  = degi1 + NT;
  int* cur1  = ofs1 + NT;
  int* csr1  = cur1 + NT;
  int* degi2 = csr1 + NEDGE;
  int* ofs2  = degi2 + NT;
  int* cur2  = ofs2 + NT;
  int* csr2  = cur2 + NT;

  const int gE = NEDGE / 256;

  // CSR + degree norms (3 dispatches + 2 DMA memsets)
  hipMemsetAsync(degi1, 0, NT * sizeof(int), stream);
  hipMemsetAsync(degi2, 0, NT * sizeof(int), stream);
  k_deg2<<<2 * gE, 256, 0, stream>>>(dst1, dst2, degi1, degi2);
  k_scan2<<<2, 1024, 0, stream>>>(degi1, ofs1, cur1, dinv1, degi2, ofs2, cur2, dinv2);
  k_fill2<<<2 * gE, 256, 0, stream>>>(src1, dst1, cur1, csr1, src2, dst2, cur2, csr2);

  // fused conv chains (both sides), writes feat1/feat2/f13/f23/gfs
  k_chain<<<512, 256, 0, stream>>>(
      x1, cent1, rw1, x2, cent2, rw2, demb, initW, initb,
      W1, b1, W2, b2, W3, b3,
      ofs1, cur1, csr1, ofs2, cur2, csr2, dinv1, dinv2,
      feat1, feat2, f13, f23, gfs);

  // ged (only needs gfs; fills the gap right after chain)
  k_mlp<<<BATCH, 256, 0, stream>>>(gfs, scW1, scb1, scW2, scb2, ged);

  // both sims in one grid-512 launch
  k_sim<<<512, 1024, 0, stream>>>(feat1, feat2, f13, f23, Aaff, topk, S1, S2);
}